// Round 4
// baseline (128.369 us; speedup 1.0000x reference)
//
#include <hip/hip_runtime.h>

// Trilinear table lookup: x-plane counting sort -> persistent quad-cooperative
// gather with deep MLP.
//
// unList: [B,3] f32 in [0,1]; table: [128,128,128,8] f32; out: [B,8] f32
//
// k_main: 4 lanes/point; each (bx,by) corner-pair group is 64 B (z0,z0+1
// cells x 8ch); lane q loads float4 #q so the quad coalesces to one line.
// Each wave owns a contiguous 256-point slice of the sorted records and
// processes 64 points/iteration with all 16 gathers issued back-to-back.

#define DIM 128
#define CH 8
#define BINS 128
#define CHUNK 4096
#define PPT 16
#define REC_OFF 4096
#define NMAIN 2048   // persistent grid (multiple of 8)

__device__ __forceinline__ int key_of(float ux) {
    float sx = fminf(fmaxf(ux, 0.0f), 1.0f) * 127.0f;
    float fx0 = fminf(floorf(sx), 126.0f);
    return (int)fx0;
}

__global__ __launch_bounds__(256) void k_hist(const float* __restrict__ un,
                                              unsigned* __restrict__ hist, int batch) {
    __shared__ unsigned lh[BINS];
    for (int i = threadIdx.x; i < BINS; i += blockDim.x) lh[i] = 0;
    __syncthreads();
    int stride = gridDim.x * blockDim.x;
    for (int i = blockIdx.x * blockDim.x + threadIdx.x; i < batch; i += stride)
        atomicAdd(&lh[key_of(un[3 * i])], 1u);
    __syncthreads();
    for (int i = threadIdx.x; i < BINS; i += blockDim.x)
        if (lh[i]) atomicAdd(&hist[i], lh[i]);
}

__global__ void k_scan(const unsigned* __restrict__ hist,
                       unsigned* __restrict__ base, unsigned* __restrict__ cursor) {
    __shared__ unsigned lh[BINS];
    __shared__ unsigned lb[BINS];
    int t = threadIdx.x;
    if (t < BINS) lh[t] = hist[t];
    __syncthreads();
    if (t == 0) {
        unsigned acc = 0;
        for (int i = 0; i < BINS; ++i) { lb[i] = acc; acc += lh[i]; }
    }
    __syncthreads();
    if (t < BINS) { base[t] = lb[t]; cursor[t] = lb[t]; }
}

__global__ __launch_bounds__(256) void k_scatter(const float* __restrict__ un,
                                                 unsigned* __restrict__ cursor,
                                                 float4* __restrict__ rec, int batch) {
    __shared__ unsigned lh[BINS];
    __shared__ unsigned lbase[BINS];
    int t = threadIdx.x;
    for (int i = t; i < BINS; i += blockDim.x) lh[i] = 0;
    __syncthreads();
    int start = blockIdx.x * CHUNK;
    unsigned kr[PPT];
#pragma unroll
    for (int j = 0; j < PPT; ++j) {
        int i = start + j * 256 + t;
        if (i < batch) {
            int k = key_of(un[3 * i]);
            unsigned r = atomicAdd(&lh[k], 1u);
            kr[j] = (unsigned)k | (r << 8);
        } else kr[j] = 0xFFFFFFFFu;
    }
    __syncthreads();
    for (int i = t; i < BINS; i += blockDim.x)
        lbase[i] = lh[i] ? atomicAdd(&cursor[i], lh[i]) : 0u;
    __syncthreads();
#pragma unroll
    for (int j = 0; j < PPT; ++j) {
        int i = start + j * 256 + t;
        if (i < batch) {
            unsigned k = kr[j] & 0xFFu, r = kr[j] >> 8;
            float ux = un[3 * i], uy = un[3 * i + 1], uz = un[3 * i + 2];
            rec[lbase[k] + r] = make_float4(ux, uy, uz, __uint_as_float((unsigned)i));
        }
    }
}

// ---- persistent quad-cooperative main kernel ----
__global__ __launch_bounds__(256, 4) void k_main(const float4* __restrict__ rec,
                                                 const float* __restrict__ table,
                                                 float* __restrict__ out, int batch) {
    // XCD-aware swizzle: XCD x gets a contiguous 1/8 of the sorted order.
    int per = gridDim.x >> 3;
    int pb = blockIdx.x;
    int lb = (pb & 7) * per + (pb >> 3);

    int t = (int)threadIdx.x;
    int lane = t & 63, wave = t >> 6;
    int p = lane >> 2, q = lane & 3;

    int nw = (int)gridDim.x * 4;
    int g = lb * 4 + wave;
    // points per wave, rounded to 64
    long ppw = ((((long)batch + (long)nw * 64 - 1) / ((long)nw * 64)) * 64);
    long beg = (long)g * ppw;
    long end = beg + ppw;
    if (end > (long)batch) end = (long)batch;
    if (beg >= end) return;

    const float dmax = 127.0f, imax = 126.0f;
    const char* tb = (const char*)table;
    const unsigned qoff = (unsigned)(q << 4);   // q*16 bytes within 64B group

    long base = beg;
    for (; base + 64 <= end; base += 64) {
        // 4 sub-passes x 16 points; quad lanes broadcast-load their rec
        float4 r0 = rec[base + 0  + p];
        float4 r1 = rec[base + 16 + p];
        float4 r2 = rec[base + 32 + p];
        float4 r3 = rec[base + 48 + p];

        unsigned o_[4]; unsigned off_[4]; float w_[4][4];
#define PREP(s, rr) { \
        float sx = fminf(fmaxf(rr.x, 0.0f), 1.0f) * dmax; \
        float sy = fminf(fmaxf(rr.y, 0.0f), 1.0f) * dmax; \
        float sz = fminf(fmaxf(rr.z, 0.0f), 1.0f) * dmax; \
        float fx0 = fminf(floorf(sx), imax); \
        float fy0 = fminf(floorf(sy), imax); \
        float fz0 = fminf(floorf(sz), imax); \
        int x0 = (int)fx0, y0 = (int)fy0, z0 = (int)fz0; \
        float fx = sx - fx0, fy = sy - fy0, fz = sz - fz0; \
        float wzq = (q & 2) ? fz : (1.0f - fz); \
        float gx = 1.0f - fx, gy = 1.0f - fy; \
        w_[s][0] = gx * gy * wzq; \
        w_[s][1] = gx * fy * wzq; \
        w_[s][2] = fx * gy * wzq; \
        w_[s][3] = fx * fy * wzq; \
        off_[s] = (unsigned)(((x0 * 128 + y0) * 128 + z0) * 32) + qoff; \
        o_[s] = __float_as_uint(rr.w); }
        PREP(0, r0) PREP(1, r1) PREP(2, r2) PREP(3, r3)
#undef PREP

        // issue all 16 gathers back-to-back (independent dests -> deep MLP)
        float4 v00 = *(const float4*)(tb + off_[0]);
        float4 v01 = *(const float4*)(tb + off_[0] + 4096u);
        float4 v02 = *(const float4*)(tb + off_[0] + 524288u);
        float4 v03 = *(const float4*)(tb + off_[0] + 528384u);
        float4 v10 = *(const float4*)(tb + off_[1]);
        float4 v11 = *(const float4*)(tb + off_[1] + 4096u);
        float4 v12 = *(const float4*)(tb + off_[1] + 524288u);
        float4 v13 = *(const float4*)(tb + off_[1] + 528384u);
        float4 v20 = *(const float4*)(tb + off_[2]);
        float4 v21 = *(const float4*)(tb + off_[2] + 4096u);
        float4 v22 = *(const float4*)(tb + off_[2] + 524288u);
        float4 v23 = *(const float4*)(tb + off_[2] + 528384u);
        float4 v30 = *(const float4*)(tb + off_[3]);
        float4 v31 = *(const float4*)(tb + off_[3] + 4096u);
        float4 v32 = *(const float4*)(tb + off_[3] + 524288u);
        float4 v33 = *(const float4*)(tb + off_[3] + 528384u);

#define COMB(s, a, b, c, d) { \
        float4 acc; \
        acc.x = w_[s][0]*a.x + w_[s][1]*b.x + w_[s][2]*c.x + w_[s][3]*d.x; \
        acc.y = w_[s][0]*a.y + w_[s][1]*b.y + w_[s][2]*c.y + w_[s][3]*d.y; \
        acc.z = w_[s][0]*a.z + w_[s][1]*b.z + w_[s][2]*c.z + w_[s][3]*d.z; \
        acc.w = w_[s][0]*a.w + w_[s][1]*b.w + w_[s][2]*c.w + w_[s][3]*d.w; \
        acc.x += __shfl_xor(acc.x, 2); \
        acc.y += __shfl_xor(acc.y, 2); \
        acc.z += __shfl_xor(acc.z, 2); \
        acc.w += __shfl_xor(acc.w, 2); \
        if (q < 2) \
            *reinterpret_cast<float4*>(out + (size_t)o_[s] * CH + (q << 2)) = acc; }
        COMB(0, v00, v01, v02, v03)
        COMB(1, v10, v11, v12, v13)
        COMB(2, v20, v21, v22, v23)
        COMB(3, v30, v31, v32, v33)
#undef COMB
    }

    // tail: 16 points at a time, per-point guard
    for (; base < end; base += 16) {
        long i = base + p;
        if (i >= end) continue;
        float4 r = rec[i];
        unsigned orig = __float_as_uint(r.w);
        float sx = fminf(fmaxf(r.x, 0.0f), 1.0f) * dmax;
        float sy = fminf(fmaxf(r.y, 0.0f), 1.0f) * dmax;
        float sz = fminf(fmaxf(r.z, 0.0f), 1.0f) * dmax;
        float fx0 = fminf(floorf(sx), imax);
        float fy0 = fminf(floorf(sy), imax);
        float fz0 = fminf(floorf(sz), imax);
        int x0 = (int)fx0, y0 = (int)fy0, z0 = (int)fz0;
        float fx = sx - fx0, fy = sy - fy0, fz = sz - fz0;
        float wzq = (q & 2) ? fz : (1.0f - fz);
        float gx = 1.0f - fx, gy = 1.0f - fy;
        unsigned off = (unsigned)(((x0 * 128 + y0) * 128 + z0) * 32) + qoff;
        float4 a = *(const float4*)(tb + off);
        float4 b = *(const float4*)(tb + off + 4096u);
        float4 c = *(const float4*)(tb + off + 524288u);
        float4 d = *(const float4*)(tb + off + 528384u);
        float w0 = gx * gy * wzq, w1 = gx * fy * wzq, w2 = fx * gy * wzq, w3 = fx * fy * wzq;
        float4 acc;
        acc.x = w0*a.x + w1*b.x + w2*c.x + w3*d.x;
        acc.y = w0*a.y + w1*b.y + w2*c.y + w3*d.y;
        acc.z = w0*a.z + w1*b.z + w2*c.z + w3*d.z;
        acc.w = w0*a.w + w1*b.w + w2*c.w + w3*d.w;
        acc.x += __shfl_xor(acc.x, 2);
        acc.y += __shfl_xor(acc.y, 2);
        acc.z += __shfl_xor(acc.z, 2);
        acc.w += __shfl_xor(acc.w, 2);
        if (q < 2)
            *reinterpret_cast<float4*>(out + (size_t)orig * CH + (q << 2)) = acc;
    }
}

// Fallback (no workspace): direct gather.
__global__ __launch_bounds__(256) void k_naive(const float* __restrict__ un,
                                               const float* __restrict__ table,
                                               float* __restrict__ out, int batch) {
    int b = blockIdx.x * blockDim.x + threadIdx.x;
    if (b >= batch) return;
    float ux = un[3 * b], uy = un[3 * b + 1], uz = un[3 * b + 2];
    const float dmax = 127.0f, imax = 126.0f;
    float sx = fminf(fmaxf(ux, 0.0f), 1.0f) * dmax;
    float sy = fminf(fmaxf(uy, 0.0f), 1.0f) * dmax;
    float sz = fminf(fmaxf(uz, 0.0f), 1.0f) * dmax;
    float fx0 = fminf(floorf(sx), imax);
    float fy0 = fminf(floorf(sy), imax);
    float fz0 = fminf(floorf(sz), imax);
    int x0 = (int)fx0, y0 = (int)fy0, z0 = (int)fz0;
    float fx = sx - fx0, fy = sy - fy0, fz = sz - fz0;
    float wx[2] = {1.0f - fx, fx};
    float wy[2] = {1.0f - fy, fy};
    float wz0 = 1.0f - fz, wz1 = fz;
    float acc[CH];
#pragma unroll
    for (int c = 0; c < CH; ++c) acc[c] = 0.0f;
#pragma unroll
    for (int bx = 0; bx < 2; ++bx)
#pragma unroll
        for (int by = 0; by < 2; ++by) {
            const float* pp = table + ((size_t)((x0 + bx) * DIM + (y0 + by)) * DIM + z0) * CH;
            float wxy = wx[bx] * wy[by];
            float w0 = wxy * wz0, w1 = wxy * wz1;
            float4 a0 = *reinterpret_cast<const float4*>(pp + 0);
            float4 a1 = *reinterpret_cast<const float4*>(pp + 4);
            float4 b0 = *reinterpret_cast<const float4*>(pp + 8);
            float4 b1 = *reinterpret_cast<const float4*>(pp + 12);
            acc[0] += w0 * a0.x + w1 * b0.x;  acc[1] += w0 * a0.y + w1 * b0.y;
            acc[2] += w0 * a0.z + w1 * b0.z;  acc[3] += w0 * a0.w + w1 * b0.w;
            acc[4] += w0 * a1.x + w1 * b1.x;  acc[5] += w0 * a1.y + w1 * b1.y;
            acc[6] += w0 * a1.z + w1 * b1.z;  acc[7] += w0 * a1.w + w1 * b1.w;
        }
    float4* o = reinterpret_cast<float4*>(out + (size_t)b * CH);
    o[0] = make_float4(acc[0], acc[1], acc[2], acc[3]);
    o[1] = make_float4(acc[4], acc[5], acc[6], acc[7]);
}

extern "C" void kernel_launch(void* const* d_in, const int* in_sizes, int n_in,
                              void* d_out, int out_size, void* d_ws, size_t ws_size,
                              hipStream_t stream) {
    const float* un    = (const float*)d_in[0];
    const float* table = (const float*)d_in[1];
    float* out         = (float*)d_out;
    int batch = in_sizes[0] / 3;

    size_t need = (size_t)REC_OFF + (size_t)batch * 16;
    if (ws_size < need) {
        int grid = (batch + 255) / 256;
        k_naive<<<grid, 256, 0, stream>>>(un, table, out, batch);
        return;
    }

    unsigned* hist   = (unsigned*)d_ws;
    unsigned* base   = (unsigned*)((char*)d_ws + 512);
    unsigned* cursor = (unsigned*)((char*)d_ws + 1024);
    float4*   rec    = (float4*)((char*)d_ws + REC_OFF);

    hipMemsetAsync(d_ws, 0, 1536, stream);
    k_hist<<<512, 256, 0, stream>>>(un, hist, batch);
    k_scan<<<1, 128, 0, stream>>>(hist, base, cursor);
    int nscat = (batch + CHUNK - 1) / CHUNK;
    k_scatter<<<nscat, 256, 0, stream>>>(un, cursor, rec, batch);
    k_main<<<NMAIN, 256, 0, stream>>>(rec, table, out, batch);
}

// Round 5
// 112.674 us; speedup vs baseline: 1.1393x; 1.1393x over previous
//
#include <hip/hip_runtime.h>

// Trilinear table lookup: x-plane counting sort -> dispatch-ordered
// quad-cooperative gather with explicit 4-deep MLP.
//
// unList: [B,3] f32 in [0,1]; table: [128,128,128,8] f32; out: [B,8] f32
//
// Small dispatch-ordered blocks (64 pts) keep a narrow sliding window over
// the sorted table range (L2-resident, FETCH ~52MB — R3 evidence). The R3
// defect was serialized gathers (VGPR=16 -> MLP~1); here the 4 corner-group
// loads are issued back-to-back into distinct registers with a sched fence.

#define DIM 128
#define CH 8
#define BINS 128
#define CHUNK 4096
#define PPT 16
#define REC_OFF 4096

__device__ __forceinline__ int key_of(float ux) {
    float sx = fminf(fmaxf(ux, 0.0f), 1.0f) * 127.0f;
    float fx0 = fminf(floorf(sx), 126.0f);
    return (int)fx0;
}

__global__ __launch_bounds__(256) void k_hist(const float* __restrict__ un,
                                              unsigned* __restrict__ hist, int batch) {
    __shared__ unsigned lh[BINS];
    for (int i = threadIdx.x; i < BINS; i += blockDim.x) lh[i] = 0;
    __syncthreads();
    int stride = gridDim.x * blockDim.x;
    for (int i = blockIdx.x * blockDim.x + threadIdx.x; i < batch; i += stride)
        atomicAdd(&lh[key_of(un[3 * i])], 1u);
    __syncthreads();
    for (int i = threadIdx.x; i < BINS; i += blockDim.x)
        if (lh[i]) atomicAdd(&hist[i], lh[i]);
}

__global__ void k_scan(const unsigned* __restrict__ hist,
                       unsigned* __restrict__ base, unsigned* __restrict__ cursor) {
    __shared__ unsigned lh[BINS];
    __shared__ unsigned lb[BINS];
    int t = threadIdx.x;
    if (t < BINS) lh[t] = hist[t];
    __syncthreads();
    if (t == 0) {
        unsigned acc = 0;
        for (int i = 0; i < BINS; ++i) { lb[i] = acc; acc += lh[i]; }
    }
    __syncthreads();
    if (t < BINS) { base[t] = lb[t]; cursor[t] = lb[t]; }
}

__global__ __launch_bounds__(256) void k_scatter(const float* __restrict__ un,
                                                 unsigned* __restrict__ cursor,
                                                 float4* __restrict__ rec, int batch) {
    __shared__ unsigned lh[BINS];
    __shared__ unsigned lbase[BINS];
    int t = threadIdx.x;
    for (int i = t; i < BINS; i += blockDim.x) lh[i] = 0;
    __syncthreads();
    int start = blockIdx.x * CHUNK;
    unsigned kr[PPT];
#pragma unroll
    for (int j = 0; j < PPT; ++j) {
        int i = start + j * 256 + t;
        if (i < batch) {
            int k = key_of(un[3 * i]);
            unsigned r = atomicAdd(&lh[k], 1u);
            kr[j] = (unsigned)k | (r << 8);
        } else kr[j] = 0xFFFFFFFFu;
    }
    __syncthreads();
    for (int i = t; i < BINS; i += blockDim.x)
        lbase[i] = lh[i] ? atomicAdd(&cursor[i], lh[i]) : 0u;
    __syncthreads();
#pragma unroll
    for (int j = 0; j < PPT; ++j) {
        int i = start + j * 256 + t;
        if (i < batch) {
            unsigned k = kr[j] & 0xFFu, r = kr[j] >> 8;
            float ux = un[3 * i], uy = un[3 * i + 1], uz = un[3 * i + 2];
            rec[lbase[k] + r] = make_float4(ux, uy, uz, __uint_as_float((unsigned)i));
        }
    }
}

// Quad-cooperative main: 4 lanes/point, 16 pts/wave, 64 pts/block.
// Explicit 4-deep gather batch per lane.
__global__ __launch_bounds__(256) void k_main(const float4* __restrict__ rec,
                                              const float* __restrict__ table,
                                              float* __restrict__ out, int batch) {
    // XCD-aware swizzle (gridDim.x % 8 == 0 by launch)
    int per = gridDim.x >> 3;
    int pb = blockIdx.x;
    int lb = (pb & 7) * per + (pb >> 3);

    int t = (int)threadIdx.x;
    int lane = t & 63;
    int wave = t >> 6;
    int p = lane >> 2;        // point within wave: 0..15
    int q = lane & 3;         // quad sub-lane

    int i = lb * 64 + wave * 16 + p;
    if (i >= batch) return;

    float4 r = rec[i];
    unsigned orig = __float_as_uint(r.w);

    const float dmax = 127.0f, imax = 126.0f;
    float sx = fminf(fmaxf(r.x, 0.0f), 1.0f) * dmax;
    float sy = fminf(fmaxf(r.y, 0.0f), 1.0f) * dmax;
    float sz = fminf(fmaxf(r.z, 0.0f), 1.0f) * dmax;
    float fx0 = fminf(floorf(sx), imax);
    float fy0 = fminf(floorf(sy), imax);
    float fz0 = fminf(floorf(sz), imax);
    int x0 = (int)fx0, y0 = (int)fy0, z0 = (int)fz0;
    float fx = sx - fx0, fy = sy - fy0, fz = sz - fz0;

    float wzq = (q & 2) ? fz : (1.0f - fz);   // this lane's z-corner weight
    float gx = 1.0f - fx, gy = 1.0f - fy;
    float w0 = gx * gy * wzq;   // (x0  , y0  )
    float w1 = gx * fy * wzq;   // (x0  , y0+1)
    float w2 = fx * gy * wzq;   // (x0+1, y0  )
    float w3 = fx * fy * wzq;   // (x0+1, y0+1)

    // u32 byte offset of (x0,y0,z0,ch0) + this lane's 16B slot in the 64B group
    unsigned off = (unsigned)(((x0 * DIM + y0) * DIM + z0) * 32) + (unsigned)(q << 4);
    const char* tb = (const char*)table;

    // issue all four corner-group gathers back-to-back (distinct dests)
    float4 v0 = *(const float4*)(tb + off);              // (x0  , y0  )
    float4 v1 = *(const float4*)(tb + off + 4096u);      // (x0  , y0+1) +128*32B
    float4 v2 = *(const float4*)(tb + off + 524288u);    // (x0+1, y0  ) +128*128*32B
    float4 v3 = *(const float4*)(tb + off + 528384u);    // (x0+1, y0+1)
    __builtin_amdgcn_sched_barrier(0);   // don't sink loads below first use

    float4 acc;
    acc.x = w0 * v0.x + w1 * v1.x + w2 * v2.x + w3 * v3.x;
    acc.y = w0 * v0.y + w1 * v1.y + w2 * v2.y + w3 * v3.y;
    acc.z = w0 * v0.z + w1 * v1.z + w2 * v2.z + w3 * v3.z;
    acc.w = w0 * v0.w + w1 * v1.w + w2 * v2.w + w3 * v3.w;

    // combine z-corners across the quad (partner q^2)
    acc.x += __shfl_xor(acc.x, 2);
    acc.y += __shfl_xor(acc.y, 2);
    acc.z += __shfl_xor(acc.z, 2);
    acc.w += __shfl_xor(acc.w, 2);

    if (q < 2)
        *reinterpret_cast<float4*>(out + (size_t)orig * CH + (q << 2)) = acc;
}

// Fallback (no workspace): direct gather.
__global__ __launch_bounds__(256) void k_naive(const float* __restrict__ un,
                                               const float* __restrict__ table,
                                               float* __restrict__ out, int batch) {
    int b = blockIdx.x * blockDim.x + threadIdx.x;
    if (b >= batch) return;
    float ux = un[3 * b], uy = un[3 * b + 1], uz = un[3 * b + 2];
    const float dmax = 127.0f, imax = 126.0f;
    float sx = fminf(fmaxf(ux, 0.0f), 1.0f) * dmax;
    float sy = fminf(fmaxf(uy, 0.0f), 1.0f) * dmax;
    float sz = fminf(fmaxf(uz, 0.0f), 1.0f) * dmax;
    float fx0 = fminf(floorf(sx), imax);
    float fy0 = fminf(floorf(sy), imax);
    float fz0 = fminf(floorf(sz), imax);
    int x0 = (int)fx0, y0 = (int)fy0, z0 = (int)fz0;
    float fx = sx - fx0, fy = sy - fy0, fz = sz - fz0;
    float wx[2] = {1.0f - fx, fx};
    float wy[2] = {1.0f - fy, fy};
    float wz0 = 1.0f - fz, wz1 = fz;
    float acc[CH];
#pragma unroll
    for (int c = 0; c < CH; ++c) acc[c] = 0.0f;
#pragma unroll
    for (int bx = 0; bx < 2; ++bx)
#pragma unroll
        for (int by = 0; by < 2; ++by) {
            const float* pp = table + ((size_t)((x0 + bx) * DIM + (y0 + by)) * DIM + z0) * CH;
            float wxy = wx[bx] * wy[by];
            float w0 = wxy * wz0, w1 = wxy * wz1;
            float4 a0 = *reinterpret_cast<const float4*>(pp + 0);
            float4 a1 = *reinterpret_cast<const float4*>(pp + 4);
            float4 b0 = *reinterpret_cast<const float4*>(pp + 8);
            float4 b1 = *reinterpret_cast<const float4*>(pp + 12);
            acc[0] += w0 * a0.x + w1 * b0.x;  acc[1] += w0 * a0.y + w1 * b0.y;
            acc[2] += w0 * a0.z + w1 * b0.z;  acc[3] += w0 * a0.w + w1 * b0.w;
            acc[4] += w0 * a1.x + w1 * b1.x;  acc[5] += w0 * a1.y + w1 * b1.y;
            acc[6] += w0 * a1.z + w1 * b1.z;  acc[7] += w0 * a1.w + w1 * b1.w;
        }
    float4* o = reinterpret_cast<float4*>(out + (size_t)b * CH);
    o[0] = make_float4(acc[0], acc[1], acc[2], acc[3]);
    o[1] = make_float4(acc[4], acc[5], acc[6], acc[7]);
}

extern "C" void kernel_launch(void* const* d_in, const int* in_sizes, int n_in,
                              void* d_out, int out_size, void* d_ws, size_t ws_size,
                              hipStream_t stream) {
    const float* un    = (const float*)d_in[0];
    const float* table = (const float*)d_in[1];
    float* out         = (float*)d_out;
    int batch = in_sizes[0] / 3;

    size_t need = (size_t)REC_OFF + (size_t)batch * 16;
    if (ws_size < need) {
        int grid = (batch + 255) / 256;
        k_naive<<<grid, 256, 0, stream>>>(un, table, out, batch);
        return;
    }

    unsigned* hist   = (unsigned*)d_ws;
    unsigned* base   = (unsigned*)((char*)d_ws + 512);
    unsigned* cursor = (unsigned*)((char*)d_ws + 1024);
    float4*   rec    = (float4*)((char*)d_ws + REC_OFF);

    hipMemsetAsync(d_ws, 0, 1536, stream);
    k_hist<<<512, 256, 0, stream>>>(un, hist, batch);
    k_scan<<<1, 128, 0, stream>>>(hist, base, cursor);
    int nscat = (batch + CHUNK - 1) / CHUNK;
    k_scatter<<<nscat, 256, 0, stream>>>(un, cursor, rec, batch);
    // 64 points per block (4 waves x 16 points)
    int nmain = (batch + 63) / 64;
    nmain = ((nmain + 7) / 8) * 8;   // multiple of 8 for XCD swizzle
    k_main<<<nmain, 256, 0, stream>>>(rec, table, out, batch);
}